// Round 2
// baseline (492.770 us; speedup 1.0000x reference)
//
#include <hip/hip_runtime.h>
#include <stdint.h>

typedef uint32_t u32;
typedef __attribute__((ext_vector_type(8))) short short8;  // 8 bf16 (4 VGPRs) - MFMA A/B frag
typedef __attribute__((ext_vector_type(4))) float f32x4;   // MFMA C/D frag

#define MREAL 50000
#define NBLK  782        // ceil(50000/64)

__device__ __forceinline__ float bits2f(u32 b) { float f; __builtin_memcpy(&f, &b, 4); return f; }
__device__ __forceinline__ float bf2f(unsigned short h) { return bits2f(((u32)h) << 16); }
__device__ __forceinline__ unsigned short f2bf(float f) {
    u32 u; __builtin_memcpy(&u, &f, 4);
    u32 r = u + 0x7FFFu + ((u >> 16) & 1u);   // RNE
    return (unsigned short)(r >> 16);
}
__device__ __forceinline__ void addbf8(uint4 v, float a[8]) {
    a[0] += bits2f(v.x << 16); a[1] += bits2f(v.x & 0xFFFF0000u);
    a[2] += bits2f(v.y << 16); a[3] += bits2f(v.y & 0xFFFF0000u);
    a[4] += bits2f(v.z << 16); a[5] += bits2f(v.z & 0xFFFF0000u);
    a[6] += bits2f(v.w << 16); a[7] += bits2f(v.w & 0xFFFF0000u);
}

// ---------------------------------------------------------------------------
// x0 (f32) -> bf16, 8 elements/thread.  12.8M elems = 6250 blocks x 256 x 8.
// ---------------------------------------------------------------------------
__global__ void cvt_kernel(const float* __restrict__ in, unsigned short* __restrict__ out) {
    long i = ((long)blockIdx.x * 256 + threadIdx.x) * 8;
    float4 a = *(const float4*)(in + i);
    float4 b = *(const float4*)(in + i + 4);
    uint4 o;
    o.x = (u32)f2bf(a.x) | ((u32)f2bf(a.y) << 16);
    o.y = (u32)f2bf(a.z) | ((u32)f2bf(a.w) << 16);
    o.z = (u32)f2bf(b.x) | ((u32)f2bf(b.y) << 16);
    o.w = (u32)f2bf(b.z) | ((u32)f2bf(b.w) << 16);
    *(uint4*)(out + i) = o;
}

// ---------------------------------------------------------------------------
// Prep: Bt[step][kc][n][kkr] = bf16 of B^T chunk-packed, B = [Ws + I ; Wn]
// (512x256 per step, f32 inputs).  Also b2 = bs + bn (f32).
// ---------------------------------------------------------------------------
__global__ void prep_kernel(const float* __restrict__ Ws,
                            const float* __restrict__ bs,
                            const float* __restrict__ Wn,
                            const float* __restrict__ bn,
                            unsigned short* __restrict__ Bt,
                            float* __restrict__ b2) {
    int lin = blockIdx.x * 256 + threadIdx.x;      // 3*16*256*32 = 393216 total
    int kkr = lin & 31;
    int n   = (lin >> 5) & 255;
    int kc  = (lin >> 13) & 15;
    int s   = lin >> 17;
    int kk  = kc * 32 + kkr;
    float v;
    if (kk < 256) v = Ws[(s * 256 + kk) * 256 + n] + (kk == n ? 1.0f : 0.0f);
    else          v = Wn[(s * 256 + (kk - 256)) * 256 + n];
    Bt[lin] = f2bf(v);
    if (lin < 768) b2[lin] = bs[lin] + bn[lin];
}

// ---------------------------------------------------------------------------
// One fused step: y = [x | neigh_mean] @ [Ws+I ; Wn] + (bs+bn); LN; ReLU.
// BM=64 rows/block, full 256-col width, 4 waves, each wave 64x64 (4x4 MFMA).
// src is bf16 state; dst is bf16 (intermediate) or f32 (final, OUTF32).
// ---------------------------------------------------------------------------
template <bool OUTF32>
__global__ __launch_bounds__(256, 3) void step_kernel(
    const unsigned short* __restrict__ src,   // x (bf16, 50000x256)
    void* __restrict__ dstv,                  // bf16 or f32, 50000x256
    const unsigned short* __restrict__ Bt,    // this step's [16][256][32] bf16
    const float* __restrict__ b2,             // [256] combined bias (f32)
    const float* __restrict__ lnS,            // [256] ln_scale f32
    const float* __restrict__ lnO,            // [256] ln_offset f32
    const int* __restrict__ nbr)              // [50000][6]
{
    __shared__ unsigned short AcNm[64][264];  // neighbor-mean tile (+8 pad)
    __shared__ unsigned short Bsh[256][40];   // B^T k-chunk (+8 pad)

    const int t    = threadIdx.x;
    const int wv   = t >> 6;
    const int lane = t & 63;
    const int lo16 = lane & 15;
    const int quad = lane >> 4;
    const long r0  = (long)blockIdx.x * 64;

    // ---------- P0: gather neighbor mean into AcNm ----------
    {
        const int rl = t >> 2;          // 0..63: local row
        const int q  = t & 3;           // quarter of the 256 cols
        long rg = r0 + rl;
        long rc = rg < (MREAL - 1) ? rg : (long)(MREAL - 1);   // clamp tail rows
        const int* nb = nbr + rc * 6;
        const long o0 = (long)nb[0] * 256, o1 = (long)nb[1] * 256, o2 = (long)nb[2] * 256;
        const long o3 = (long)nb[3] * 256, o4 = (long)nb[4] * 256, o5 = (long)nb[5] * 256;
        const float inv6 = 1.0f / 6.0f;
        #pragma unroll
        for (int g = 0; g < 8; ++g) {
            const int c0 = (q * 8 + g) * 8;
            uint4 v0 = *(const uint4*)(src + o0 + c0);
            uint4 v1 = *(const uint4*)(src + o1 + c0);
            uint4 v2 = *(const uint4*)(src + o2 + c0);
            uint4 v3 = *(const uint4*)(src + o3 + c0);
            uint4 v4 = *(const uint4*)(src + o4 + c0);
            uint4 v5 = *(const uint4*)(src + o5 + c0);
            float a[8] = {0, 0, 0, 0, 0, 0, 0, 0};
            addbf8(v0, a); addbf8(v1, a); addbf8(v2, a);
            addbf8(v3, a); addbf8(v4, a); addbf8(v5, a);
            uint4 o;
            o.x = (u32)f2bf(a[0] * inv6) | ((u32)f2bf(a[1] * inv6) << 16);
            o.y = (u32)f2bf(a[2] * inv6) | ((u32)f2bf(a[3] * inv6) << 16);
            o.z = (u32)f2bf(a[4] * inv6) | ((u32)f2bf(a[5] * inv6) << 16);
            o.w = (u32)f2bf(a[6] * inv6) | ((u32)f2bf(a[7] * inv6) << 16);
            *(uint4*)&AcNm[rl][c0] = o;
        }
    }

    // ---------- K-loop: C = [x | nm] @ B  (K = 512, 16 chunks of 32) ----------
    const f32x4 zero4 = {0.f, 0.f, 0.f, 0.f};
    f32x4 acc[4][4];
    #pragma unroll
    for (int mf = 0; mf < 4; ++mf)
        #pragma unroll
        for (int nf = 0; nf < 4; ++nf) acc[mf][nf] = zero4;

    // A-row global pointers (clamped for the tail block)
    const unsigned short* aptr[4];
    #pragma unroll
    for (int mf = 0; mf < 4; ++mf) {
        long r = r0 + mf * 16 + lo16;
        if (r >= MREAL) r = MREAL - 1;
        aptr[mf] = src + r * 256 + quad * 8;
    }

    const int bn_ = t >> 2;             // Bs staging row
    const int bk0 = (t & 3) * 8;        // Bs staging k-offset
    const unsigned short* btp = Bt + (long)t * 8;

    uint4 bpre[4];
    #pragma unroll
    for (int it = 0; it < 4; ++it) bpre[it] = *(const uint4*)(btp + it * 2048);
    uint4 apre[4];
    #pragma unroll
    for (int mf = 0; mf < 4; ++mf) apre[mf] = *(const uint4*)(aptr[mf]);

    #pragma unroll
    for (int k = 0; k < 16; ++k) {
        __syncthreads();                               // all waves done reading Bsh
        *(uint4*)&Bsh[bn_      ][bk0] = bpre[0];
        *(uint4*)&Bsh[bn_ +  64][bk0] = bpre[1];
        *(uint4*)&Bsh[bn_ + 128][bk0] = bpre[2];
        *(uint4*)&Bsh[bn_ + 192][bk0] = bpre[3];
        uint4 acur[4];
        #pragma unroll
        for (int mf = 0; mf < 4; ++mf) acur[mf] = apre[mf];
        if (k < 15) {
            #pragma unroll
            for (int it = 0; it < 4; ++it)
                bpre[it] = *(const uint4*)(btp + (k + 1) * 8192 + it * 2048);
            const int kn = k + 1;
            if (kn < 8) {                              // x-half: global (L2-hot)
                #pragma unroll
                for (int mf = 0; mf < 4; ++mf)
                    apre[mf] = *(const uint4*)(aptr[mf] + kn * 32);
            } else {                                   // nm-half: LDS
                #pragma unroll
                for (int mf = 0; mf < 4; ++mf)
                    apre[mf] = *(const uint4*)&AcNm[mf * 16 + lo16][(kn - 8) * 32 + quad * 8];
            }
        }
        __syncthreads();                               // Bsh staged
        short8 bfrag[4];
        #pragma unroll
        for (int nf = 0; nf < 4; ++nf)
            bfrag[nf] = *(const short8*)&Bsh[wv * 64 + nf * 16 + lo16][quad * 8];
        #pragma unroll
        for (int mf = 0; mf < 4; ++mf) {
            short8 afrag = __builtin_bit_cast(short8, acur[mf]);
            #pragma unroll
            for (int nf = 0; nf < 4; ++nf)
                acc[mf][nf] = __builtin_amdgcn_mfma_f32_16x16x32_bf16(afrag, bfrag[nf], acc[mf][nf], 0, 0, 0);
        }
    }

    // ---------- Epilogue: bias + LN + ReLU, fully fused ----------
    __syncthreads();                                   // Bsh now reusable as scratch
    float* srp  = (float*)&Bsh[0][0];                  // [64][4][2] partial sums
    float* srow = srp + 512;                           // [64][2] mean/rstd

    float biasc[4], gc[4], oc[4];
    #pragma unroll
    for (int nf = 0; nf < 4; ++nf) {
        int col = wv * 64 + nf * 16 + lo16;
        biasc[nf] = b2[col];
        gc[nf] = lnS[col];
        oc[nf] = lnO[col];
    }
    #pragma unroll
    for (int mf = 0; mf < 4; ++mf)
        #pragma unroll
        for (int nf = 0; nf < 4; ++nf) acc[mf][nf] += biasc[nf];

    #pragma unroll
    for (int mf = 0; mf < 4; ++mf) {
        float s1[4], s2[4];
        #pragma unroll
        for (int r = 0; r < 4; ++r) {
            float v0 = acc[mf][0][r], v1 = acc[mf][1][r], v2 = acc[mf][2][r], v3 = acc[mf][3][r];
            s1[r] = v0 + v1 + v2 + v3;
            s2[r] = v0 * v0 + v1 * v1 + v2 * v2 + v3 * v3;
        }
        #pragma unroll
        for (int d = 1; d < 16; d <<= 1) {
            #pragma unroll
            for (int r = 0; r < 4; ++r) {
                s1[r] += __shfl_xor(s1[r], d, 64);
                s2[r] += __shfl_xor(s2[r], d, 64);
            }
        }
        if (lo16 == 0) {
            int row = mf * 16 + quad * 4;
            #pragma unroll
            for (int r = 0; r < 4; ++r) {
                srp[(row + r) * 8 + wv * 2    ] = s1[r];
                srp[(row + r) * 8 + wv * 2 + 1] = s2[r];
            }
        }
    }
    __syncthreads();
    if (t < 64) {
        float S1 = 0.f, S2 = 0.f;
        #pragma unroll
        for (int w = 0; w < 4; ++w) { S1 += srp[t * 8 + w * 2]; S2 += srp[t * 8 + w * 2 + 1]; }
        float mean = S1 * (1.0f / 256.0f);
        float var  = S2 * (1.0f / 256.0f) - mean * mean;
        float rstd = rsqrtf(var + 1e-5f);
        srow[t * 2] = mean; srow[t * 2 + 1] = rstd;
    }
    __syncthreads();
    #pragma unroll
    for (int mf = 0; mf < 4; ++mf) {
        #pragma unroll
        for (int r = 0; r < 4; ++r) {
            int row = mf * 16 + quad * 4 + r;
            float mean = srow[row * 2], rstd = srow[row * 2 + 1];
            long rg = r0 + row;
            if (rg < MREAL) {
                #pragma unroll
                for (int nf = 0; nf < 4; ++nf) {
                    float v = (acc[mf][nf][r] - mean) * rstd * gc[nf] + oc[nf];
                    v = fmaxf(v, 0.0f);
                    long idx = rg * 256 + wv * 64 + nf * 16 + lo16;
                    if (OUTF32) ((float*)dstv)[idx] = v;
                    else        ((unsigned short*)dstv)[idx] = f2bf(v);
                }
            }
        }
    }
}

// ---------------------------------------------------------------------------
extern "C" void kernel_launch(void* const* d_in, const int* in_sizes, int n_in,
                              void* d_out, int out_size, void* d_ws, size_t ws_size,
                              hipStream_t stream) {
    const float* x0  = (const float*)d_in[0];  // 50000x256 f32
    const float* Ws  = (const float*)d_in[1];  // 3x256x256 f32
    const float* bs  = (const float*)d_in[2];  // 3x256 f32
    const float* Wn  = (const float*)d_in[3];  // 3x256x256 f32
    const float* bn  = (const float*)d_in[4];  // 3x256 f32
    const float* lnS = (const float*)d_in[5];  // 3x256 f32
    const float* lnO = (const float*)d_in[6];  // 3x256 f32
    const int* nbr   = (const int*)d_in[7];    // 50000x6 i32

    char* ws = (char*)d_ws;
    const size_t XBYTES = (size_t)MREAL * 256 * 2;               // 25,600,000 (bf16 state)
    unsigned short* xbf = (unsigned short*)ws;
    unsigned short* xA  = (unsigned short*)(ws + XBYTES);
    unsigned short* Bt  = (unsigned short*)(ws + 2 * XBYTES);    // 786,432 B
    float*          b2  = (float*)(ws + 2 * XBYTES + 786432);    // 3,072 B

    cvt_kernel <<<6250, 256, 0, stream>>>(x0, xbf);              // 6250*256*8 = 12.8M
    prep_kernel<<<1536, 256, 0, stream>>>(Ws, bs, Wn, bn, Bt, b2);
    step_kernel<false><<<NBLK, 256, 0, stream>>>(xbf, (void*)xA,  Bt,          b2,       lnS,       lnO,       nbr);
    step_kernel<false><<<NBLK, 256, 0, stream>>>(xA,  (void*)xbf, Bt + 131072, b2 + 256, lnS + 256, lnO + 256, nbr);
    step_kernel<true> <<<NBLK, 256, 0, stream>>>(xbf, d_out,      Bt + 262144, b2 + 512, lnS + 512, lnO + 512, nbr);
}

// Round 4
// 438.619 us; speedup vs baseline: 1.1235x; 1.1235x over previous
//
#include <hip/hip_runtime.h>
#include <stdint.h>

typedef uint32_t u32;
typedef __attribute__((ext_vector_type(8))) short short8;  // 8 bf16 (4 VGPRs) - MFMA A/B frag
typedef __attribute__((ext_vector_type(4))) float f32x4;   // MFMA C/D frag

#define MREAL 50000
#define NBLK  784        // 8 XCD stripes x 98 blocks x 64 rows = 50176 (>= 50000)

__device__ __forceinline__ float bits2f(u32 b) { float f; __builtin_memcpy(&f, &b, 4); return f; }
__device__ __forceinline__ float bf2f(unsigned short h) { return bits2f(((u32)h) << 16); }
__device__ __forceinline__ unsigned short f2bf(float f) {
    u32 u; __builtin_memcpy(&u, &f, 4);
    u32 r = u + 0x7FFFu + ((u >> 16) & 1u);   // RNE
    return (unsigned short)(r >> 16);
}
__device__ __forceinline__ void addbf8(uint4 v, float a[8]) {
    a[0] += bits2f(v.x << 16); a[1] += bits2f(v.x & 0xFFFF0000u);
    a[2] += bits2f(v.y << 16); a[3] += bits2f(v.y & 0xFFFF0000u);
    a[4] += bits2f(v.z << 16); a[5] += bits2f(v.z & 0xFFFF0000u);
    a[6] += bits2f(v.w << 16); a[7] += bits2f(v.w & 0xFFFF0000u);
}

// ---------------------------------------------------------------------------
// x0 (f32) -> bf16, 8 elements/thread.
// ---------------------------------------------------------------------------
__global__ void cvt_kernel(const float* __restrict__ in, unsigned short* __restrict__ out) {
    long i = ((long)blockIdx.x * 256 + threadIdx.x) * 8;
    float4 a = *(const float4*)(in + i);
    float4 b = *(const float4*)(in + i + 4);
    uint4 o;
    o.x = (u32)f2bf(a.x) | ((u32)f2bf(a.y) << 16);
    o.y = (u32)f2bf(a.z) | ((u32)f2bf(a.w) << 16);
    o.z = (u32)f2bf(b.x) | ((u32)f2bf(b.y) << 16);
    o.w = (u32)f2bf(b.z) | ((u32)f2bf(b.w) << 16);
    *(uint4*)(out + i) = o;
}

// ---------------------------------------------------------------------------
// Prep: Bt[step][kc][n][kkr] = bf16 of B^T chunk-packed, B = [Ws + I ; Wn]
// (512x256 per step, f32 inputs).  Also b2 = bs + bn (f32).
// ---------------------------------------------------------------------------
__global__ void prep_kernel(const float* __restrict__ Ws,
                            const float* __restrict__ bs,
                            const float* __restrict__ Wn,
                            const float* __restrict__ bn,
                            unsigned short* __restrict__ Bt,
                            float* __restrict__ b2) {
    int lin = blockIdx.x * 256 + threadIdx.x;      // 3*16*256*32 = 393216 total
    int kkr = lin & 31;
    int n   = (lin >> 5) & 255;
    int kc  = (lin >> 13) & 15;
    int s   = lin >> 17;
    int kk  = kc * 32 + kkr;
    float v;
    if (kk < 256) v = Ws[(s * 256 + kk) * 256 + n] + (kk == n ? 1.0f : 0.0f);
    else          v = Wn[(s * 256 + (kk - 256)) * 256 + n];
    Bt[lin] = f2bf(v);
    if (lin < 768) b2[lin] = bs[lin] + bn[lin];
}

// ---------------------------------------------------------------------------
// One fused step: y = [x | neigh_mean] @ [Ws+I ; Wn] + (bs+bn); LN; ReLU.
// BM=64 rows/block, full 256-col width, 4 waves, each wave 64x64 (4x4 MFMA).
// XCD-stripe swizzle: block b -> XCD b&7 owns contiguous rows, so the gather
// working set (stripe + Fibonacci-neighbor halo ~3.6 MB) lives in that XCD's
// 4 MB L2 instead of being re-fetched from HBM ~6x.
// ---------------------------------------------------------------------------
template <bool OUTF32>
__global__ __launch_bounds__(256, 3) void step_kernel(
    const unsigned short* __restrict__ src,   // x (bf16, 50000x256)
    void* __restrict__ dstv,                  // bf16 or f32, 50000x256
    const unsigned short* __restrict__ Bt,    // this step's [16][256][32] bf16
    const float* __restrict__ b2,             // [256] combined bias (f32)
    const float* __restrict__ lnS,            // [256] ln_scale f32
    const float* __restrict__ lnO,            // [256] ln_offset f32
    const int* __restrict__ nbr)              // [50000][6]
{
    __shared__ unsigned short AcNm[64][264];  // neighbor-mean tile (+8 pad); reused as output stage
    __shared__ unsigned short Bsh[256][40];   // B^T k-chunk (+8 pad); reused as LN scratch

    const int t    = threadIdx.x;
    const int wv   = t >> 6;
    const int lane = t & 63;
    const int lo16 = lane & 15;
    const int quad = lane >> 4;
    // XCD-stripe mapping: blocks b with b&7==x are dispatched to XCD x (round-
    // robin heuristic); give XCD x the contiguous row stripe [x*6272, ...).
    const long r0  = ((long)(blockIdx.x & 7) * 98 + (blockIdx.x >> 3)) * 64;

    // ---------- P0: gather neighbor mean into AcNm ----------
    {
        const int rl = t >> 2;          // 0..63: local row
        const int q  = t & 3;           // quarter of the 256 cols
        long rg = r0 + rl;
        long rc = rg < (MREAL - 1) ? rg : (long)(MREAL - 1);   // clamp tail rows
        const int* nb = nbr + rc * 6;
        const long o0 = (long)nb[0] * 256, o1 = (long)nb[1] * 256, o2 = (long)nb[2] * 256;
        const long o3 = (long)nb[3] * 256, o4 = (long)nb[4] * 256, o5 = (long)nb[5] * 256;
        const float inv6 = 1.0f / 6.0f;
        #pragma unroll
        for (int g = 0; g < 8; ++g) {
            const int c0 = (q * 8 + g) * 8;
            uint4 v0 = *(const uint4*)(src + o0 + c0);
            uint4 v1 = *(const uint4*)(src + o1 + c0);
            uint4 v2 = *(const uint4*)(src + o2 + c0);
            uint4 v3 = *(const uint4*)(src + o3 + c0);
            uint4 v4 = *(const uint4*)(src + o4 + c0);
            uint4 v5 = *(const uint4*)(src + o5 + c0);
            float a[8] = {0, 0, 0, 0, 0, 0, 0, 0};
            addbf8(v0, a); addbf8(v1, a); addbf8(v2, a);
            addbf8(v3, a); addbf8(v4, a); addbf8(v5, a);
            uint4 o;
            o.x = (u32)f2bf(a[0] * inv6) | ((u32)f2bf(a[1] * inv6) << 16);
            o.y = (u32)f2bf(a[2] * inv6) | ((u32)f2bf(a[3] * inv6) << 16);
            o.z = (u32)f2bf(a[4] * inv6) | ((u32)f2bf(a[5] * inv6) << 16);
            o.w = (u32)f2bf(a[6] * inv6) | ((u32)f2bf(a[7] * inv6) << 16);
            *(uint4*)&AcNm[rl][c0] = o;
        }
    }

    // ---------- K-loop: C = [x | nm] @ B  (K = 512, 16 chunks of 32) ----------
    const f32x4 zero4 = {0.f, 0.f, 0.f, 0.f};
    f32x4 acc[4][4];
    #pragma unroll
    for (int mf = 0; mf < 4; ++mf)
        #pragma unroll
        for (int nf = 0; nf < 4; ++nf) acc[mf][nf] = zero4;

    // A-row global pointers (clamped for the tail block)
    const unsigned short* aptr[4];
    #pragma unroll
    for (int mf = 0; mf < 4; ++mf) {
        long r = r0 + mf * 16 + lo16;
        if (r >= MREAL) r = MREAL - 1;
        aptr[mf] = src + r * 256 + quad * 8;
    }

    const int bn_ = t >> 2;             // Bs staging row
    const int bk0 = (t & 3) * 8;        // Bs staging k-offset
    const unsigned short* btp = Bt + (long)t * 8;

    uint4 bpre[4];
    #pragma unroll
    for (int it = 0; it < 4; ++it) bpre[it] = *(const uint4*)(btp + it * 2048);
    uint4 apre[4];
    #pragma unroll
    for (int mf = 0; mf < 4; ++mf) apre[mf] = *(const uint4*)(aptr[mf]);

    #pragma unroll
    for (int k = 0; k < 16; ++k) {
        __syncthreads();                               // all waves done reading Bsh
        *(uint4*)&Bsh[bn_      ][bk0] = bpre[0];
        *(uint4*)&Bsh[bn_ +  64][bk0] = bpre[1];
        *(uint4*)&Bsh[bn_ + 128][bk0] = bpre[2];
        *(uint4*)&Bsh[bn_ + 192][bk0] = bpre[3];
        uint4 acur[4];
        #pragma unroll
        for (int mf = 0; mf < 4; ++mf) acur[mf] = apre[mf];
        if (k < 15) {
            #pragma unroll
            for (int it = 0; it < 4; ++it)
                bpre[it] = *(const uint4*)(btp + (k + 1) * 8192 + it * 2048);
            const int kn = k + 1;
            if (kn < 8) {                              // x-half: global (L2-hot)
                #pragma unroll
                for (int mf = 0; mf < 4; ++mf)
                    apre[mf] = *(const uint4*)(aptr[mf] + kn * 32);
            } else {                                   // nm-half: LDS
                #pragma unroll
                for (int mf = 0; mf < 4; ++mf)
                    apre[mf] = *(const uint4*)&AcNm[mf * 16 + lo16][(kn - 8) * 32 + quad * 8];
            }
        }
        __syncthreads();                               // Bsh staged
        short8 bfrag[4];
        #pragma unroll
        for (int nf = 0; nf < 4; ++nf)
            bfrag[nf] = *(const short8*)&Bsh[wv * 64 + nf * 16 + lo16][quad * 8];
        #pragma unroll
        for (int mf = 0; mf < 4; ++mf) {
            short8 afrag = __builtin_bit_cast(short8, acur[mf]);
            #pragma unroll
            for (int nf = 0; nf < 4; ++nf)
                acc[mf][nf] = __builtin_amdgcn_mfma_f32_16x16x32_bf16(afrag, bfrag[nf], acc[mf][nf], 0, 0, 0);
        }
    }

    // ---------- Epilogue: bias + LN + ReLU, fully fused ----------
    __syncthreads();                                   // Bsh/AcNm now reusable as scratch
    float* srp  = (float*)&Bsh[0][0];                  // [64][4][2] partial sums
    float* srow = srp + 512;                           // [64][2] mean/rstd

    float biasc[4], gc[4], oc[4];
    #pragma unroll
    for (int nf = 0; nf < 4; ++nf) {
        int col = wv * 64 + nf * 16 + lo16;
        biasc[nf] = b2[col];
        gc[nf] = lnS[col];
        oc[nf] = lnO[col];
    }
    #pragma unroll
    for (int mf = 0; mf < 4; ++mf)
        #pragma unroll
        for (int nf = 0; nf < 4; ++nf) acc[mf][nf] += biasc[nf];

    #pragma unroll
    for (int mf = 0; mf < 4; ++mf) {
        float s1[4], s2[4];
        #pragma unroll
        for (int r = 0; r < 4; ++r) {
            float v0 = acc[mf][0][r], v1 = acc[mf][1][r], v2 = acc[mf][2][r], v3 = acc[mf][3][r];
            s1[r] = v0 + v1 + v2 + v3;
            s2[r] = v0 * v0 + v1 * v1 + v2 * v2 + v3 * v3;
        }
        #pragma unroll
        for (int d = 1; d < 16; d <<= 1) {
            #pragma unroll
            for (int r = 0; r < 4; ++r) {
                s1[r] += __shfl_xor(s1[r], d, 64);
                s2[r] += __shfl_xor(s2[r], d, 64);
            }
        }
        if (lo16 == 0) {
            int row = mf * 16 + quad * 4;
            #pragma unroll
            for (int r = 0; r < 4; ++r) {
                srp[(row + r) * 8 + wv * 2    ] = s1[r];
                srp[(row + r) * 8 + wv * 2 + 1] = s2[r];
            }
        }
    }
    __syncthreads();
    if (t < 64) {
        float S1 = 0.f, S2 = 0.f;
        #pragma unroll
        for (int w = 0; w < 4; ++w) { S1 += srp[t * 8 + w * 2]; S2 += srp[t * 8 + w * 2 + 1]; }
        float mean = S1 * (1.0f / 256.0f);
        float var  = S2 * (1.0f / 256.0f) - mean * mean;
        float rstd = rsqrtf(var + 1e-5f);
        srow[t * 2] = mean; srow[t * 2 + 1] = rstd;
    }
    __syncthreads();

    // Normalize into AcNm (flat [64][256] bf16, global layout) ...
    unsigned short* obuf = &AcNm[0][0];
    #pragma unroll
    for (int mf = 0; mf < 4; ++mf) {
        #pragma unroll
        for (int r = 0; r < 4; ++r) {
            int row = mf * 16 + quad * 4 + r;
            float mean = srow[row * 2], rstd = srow[row * 2 + 1];
            #pragma unroll
            for (int nf = 0; nf < 4; ++nf) {
                float v = (acc[mf][nf][r] - mean) * rstd * gc[nf] + oc[nf];
                v = fmaxf(v, 0.0f);
                obuf[row * 256 + wv * 64 + nf * 16 + lo16] = f2bf(v);
            }
        }
    }
    __syncthreads();

    // ... then store flat & coalesced: 16 B/lane (bf16) or 32 B/lane (f32).
    #pragma unroll
    for (int it = 0; it < 8; ++it) {
        const int e = it * 2048 + t * 8;               // tile element index (8 per lane, one row)
        const long rg = r0 + (e >> 8);
        if (rg < MREAL) {
            uint4 w = *(const uint4*)(obuf + e);
            if (OUTF32) {
                float* dp = (float*)dstv + r0 * 256 + e;
                float4 f0, f1;
                f0.x = bits2f(w.x << 16); f0.y = bits2f(w.x & 0xFFFF0000u);
                f0.z = bits2f(w.y << 16); f0.w = bits2f(w.y & 0xFFFF0000u);
                f1.x = bits2f(w.z << 16); f1.y = bits2f(w.z & 0xFFFF0000u);
                f1.z = bits2f(w.w << 16); f1.w = bits2f(w.w & 0xFFFF0000u);
                *(float4*)dp = f0;
                *(float4*)(dp + 4) = f1;
            } else {
                *(uint4*)((unsigned short*)dstv + r0 * 256 + e) = w;
            }
        }
    }
}

// ---------------------------------------------------------------------------
extern "C" void kernel_launch(void* const* d_in, const int* in_sizes, int n_in,
                              void* d_out, int out_size, void* d_ws, size_t ws_size,
                              hipStream_t stream) {
    const float* x0  = (const float*)d_in[0];  // 50000x256 f32
    const float* Ws  = (const float*)d_in[1];  // 3x256x256 f32
    const float* bs  = (const float*)d_in[2];  // 3x256 f32
    const float* Wn  = (const float*)d_in[3];  // 3x256x256 f32
    const float* bn  = (const float*)d_in[4];  // 3x256 f32
    const float* lnS = (const float*)d_in[5];  // 3x256 f32
    const float* lnO = (const float*)d_in[6];  // 3x256 f32
    const int* nbr   = (const int*)d_in[7];    // 50000x6 i32

    char* ws = (char*)d_ws;
    const size_t XBYTES = (size_t)MREAL * 256 * 2;               // 25,600,000 (bf16 state)
    unsigned short* xbf = (unsigned short*)ws;
    unsigned short* xA  = (unsigned short*)(ws + XBYTES);
    unsigned short* Bt  = (unsigned short*)(ws + 2 * XBYTES);    // 786,432 B
    float*          b2  = (float*)(ws + 2 * XBYTES + 786432);    // 3,072 B

    cvt_kernel <<<6250, 256, 0, stream>>>(x0, xbf);              // 6250*256*8 = 12.8M
    prep_kernel<<<1536, 256, 0, stream>>>(Ws, bs, Wn, bn, Bt, b2);
    step_kernel<false><<<NBLK, 256, 0, stream>>>(xbf, (void*)xA,  Bt,          b2,       lnS,       lnO,       nbr);
    step_kernel<false><<<NBLK, 256, 0, stream>>>(xA,  (void*)xbf, Bt + 131072, b2 + 256, lnS + 256, lnO + 256, nbr);
    step_kernel<true> <<<NBLK, 256, 0, stream>>>(xbf, d_out,      Bt + 262144, b2 + 512, lnS + 512, lnO + 512, nbr);
}

// Round 7
// 306.662 us; speedup vs baseline: 1.6069x; 1.4303x over previous
//
#include <hip/hip_runtime.h>
#include <stdint.h>

typedef uint32_t u32;
typedef __attribute__((ext_vector_type(8))) short short8;  // 8 bf16 (4 VGPRs) - MFMA A/B frag
typedef __attribute__((ext_vector_type(4))) float f32x4;   // MFMA C/D frag

#define MREAL 50000
#define NBLK  784        // 8 XCD stripes x 98 blocks x 64 rows = 50176 (>= 50000)

__device__ __forceinline__ float bits2f(u32 b) { float f; __builtin_memcpy(&f, &b, 4); return f; }
__device__ __forceinline__ float bf2f(unsigned short h) { return bits2f(((u32)h) << 16); }
__device__ __forceinline__ unsigned short f2bf(float f) {
    u32 u; __builtin_memcpy(&u, &f, 4);
    u32 r = u + 0x7FFFu + ((u >> 16) & 1u);   // RNE
    return (unsigned short)(r >> 16);
}
__device__ __forceinline__ void addbf8(uint4 v, float a[8]) {
    a[0] += bits2f(v.x << 16); a[1] += bits2f(v.x & 0xFFFF0000u);
    a[2] += bits2f(v.y << 16); a[3] += bits2f(v.y & 0xFFFF0000u);
    a[4] += bits2f(v.z << 16); a[5] += bits2f(v.z & 0xFFFF0000u);
    a[6] += bits2f(v.w << 16); a[7] += bits2f(v.w & 0xFFFF0000u);
}

// ---------------------------------------------------------------------------
// x0 (f32) -> bf16, 8 elements/thread.
// ---------------------------------------------------------------------------
__global__ void cvt_kernel(const float* __restrict__ in, unsigned short* __restrict__ out) {
    long i = ((long)blockIdx.x * 256 + threadIdx.x) * 8;
    float4 a = *(const float4*)(in + i);
    float4 b = *(const float4*)(in + i + 4);
    uint4 o;
    o.x = (u32)f2bf(a.x) | ((u32)f2bf(a.y) << 16);
    o.y = (u32)f2bf(a.z) | ((u32)f2bf(a.w) << 16);
    o.z = (u32)f2bf(b.x) | ((u32)f2bf(b.y) << 16);
    o.w = (u32)f2bf(b.z) | ((u32)f2bf(b.w) << 16);
    *(uint4*)(out + i) = o;
}

// ---------------------------------------------------------------------------
// Prep: Bt[step][kc][n][kkr] = bf16 of B^T chunk-packed, B = [Ws + I ; Wn]
// (512x256 per step, f32 inputs).  Also b2 = bs + bn (f32).
// ---------------------------------------------------------------------------
__global__ void prep_kernel(const float* __restrict__ Ws,
                            const float* __restrict__ bs,
                            const float* __restrict__ Wn,
                            const float* __restrict__ bn,
                            unsigned short* __restrict__ Bt,
                            float* __restrict__ b2) {
    int lin = blockIdx.x * 256 + threadIdx.x;      // 3*16*256*32 = 393216 total
    int kkr = lin & 31;
    int n   = (lin >> 5) & 255;
    int kc  = (lin >> 13) & 15;
    int s   = lin >> 17;
    int kk  = kc * 32 + kkr;
    float v;
    if (kk < 256) v = Ws[(s * 256 + kk) * 256 + n] + (kk == n ? 1.0f : 0.0f);
    else          v = Wn[(s * 256 + (kk - 256)) * 256 + n];
    Bt[lin] = f2bf(v);
    if (lin < 768) b2[lin] = bs[lin] + bn[lin];
}

// ---------------------------------------------------------------------------
// One fused step: y = [x | neigh_mean] @ [Ws+I ; Wn] + (bs+bn); LN; ReLU.
// BM=64 rows/block, full 256-col width, 4 waves, each wave 64x64 (4x4 MFMA).
// Barrier-free K-loop: B-fragments read DIRECTLY from global (Bt is 256 KB,
// L2-hot per XCD; chunk-packed layout -> each (k,nf) wave read is 1 KB
// contiguous). Only barrier before the epilogue is gather->AcNm.
// NOTE: neighbor indices loaded as 3x int2 (rc*24 B is 8-aligned for all rc);
// int4 here was a misaligned-dwordx4 fault for odd rows (rounds 5/6 crash).
// ---------------------------------------------------------------------------
template <bool OUTF32>
__global__ __launch_bounds__(256, 4) void step_kernel(
    const unsigned short* __restrict__ src,   // x (bf16, 50000x256)
    void* __restrict__ dstv,                  // bf16 or f32, 50000x256
    const unsigned short* __restrict__ Bt,    // this step's [16][256][32] bf16
    const float* __restrict__ b2,             // [256] combined bias (f32)
    const float* __restrict__ lnS,            // [256] ln_scale f32
    const float* __restrict__ lnO,            // [256] ln_offset f32
    const int* __restrict__ nbr)              // [50000][6]
{
    __shared__ unsigned short AcNm[64][264];  // neighbor-mean tile (+8 pad); reused as output stage
    __shared__ float scr[640];                // LN scratch: srp[512] + srow[128]

    const int t    = threadIdx.x;
    const int wv   = t >> 6;
    const int lane = t & 63;
    const int lo16 = lane & 15;
    const int quad = lane >> 4;
    // XCD-stripe mapping: blocks b with b&7==x land on XCD x (round-robin);
    // XCD x owns the contiguous row stripe, so gather stays in its 4 MB L2.
    const long r0  = ((long)(blockIdx.x & 7) * 98 + (blockIdx.x >> 3)) * 64;

    // ---------- P0: gather neighbor mean into AcNm ----------
    {
        const int rl = t >> 2;          // 0..63: local row
        const int q  = t & 3;           // quarter of the 256 cols
        long rg = r0 + rl;
        long rc = rg < (MREAL - 1) ? rg : (long)(MREAL - 1);   // clamp tail rows
        const int* nb = nbr + rc * 6;
        const int2 n01 = *(const int2*)(nb);      // 8B-aligned for any rc
        const int2 n23 = *(const int2*)(nb + 2);
        const int2 n45 = *(const int2*)(nb + 4);
        const long o0 = (long)n01.x * 256, o1 = (long)n01.y * 256, o2 = (long)n23.x * 256;
        const long o3 = (long)n23.y * 256, o4 = (long)n45.x * 256, o5 = (long)n45.y * 256;
        const float inv6 = 1.0f / 6.0f;
        #pragma unroll
        for (int g = 0; g < 8; ++g) {
            const int c0 = (q * 8 + g) * 8;
            uint4 v0 = *(const uint4*)(src + o0 + c0);
            uint4 v1 = *(const uint4*)(src + o1 + c0);
            uint4 v2 = *(const uint4*)(src + o2 + c0);
            uint4 v3 = *(const uint4*)(src + o3 + c0);
            uint4 v4 = *(const uint4*)(src + o4 + c0);
            uint4 v5 = *(const uint4*)(src + o5 + c0);
            float a[8] = {0, 0, 0, 0, 0, 0, 0, 0};
            addbf8(v0, a); addbf8(v1, a); addbf8(v2, a);
            addbf8(v3, a); addbf8(v4, a); addbf8(v5, a);
            uint4 o;
            o.x = (u32)f2bf(a[0] * inv6) | ((u32)f2bf(a[1] * inv6) << 16);
            o.y = (u32)f2bf(a[2] * inv6) | ((u32)f2bf(a[3] * inv6) << 16);
            o.z = (u32)f2bf(a[4] * inv6) | ((u32)f2bf(a[5] * inv6) << 16);
            o.w = (u32)f2bf(a[6] * inv6) | ((u32)f2bf(a[7] * inv6) << 16);
            *(uint4*)&AcNm[rl][c0] = o;
        }
    }

    // A-row global pointers (clamped for the tail block)
    const unsigned short* aptr[4];
    #pragma unroll
    for (int mf = 0; mf < 4; ++mf) {
        long r = r0 + mf * 16 + lo16;
        if (r >= MREAL) r = MREAL - 1;
        aptr[mf] = src + r * 256 + quad * 8;
    }
    // Per-lane B base: n = wv*64 + nf*16 + lo16; element addr = n*32 + quad*8.
    const unsigned short* bbase = Bt + ((long)(wv * 64 + lo16) * 32 + quad * 8);

    const f32x4 zero4 = {0.f, 0.f, 0.f, 0.f};
    f32x4 acc[4][4];
    #pragma unroll
    for (int mf = 0; mf < 4; ++mf)
        #pragma unroll
        for (int nf = 0; nf < 4; ++nf) acc[mf][nf] = zero4;

    __syncthreads();                                   // AcNm ready — ONLY pre-epilogue barrier

    // ---------- K-loop: barrier-free, fully unrolled (K = 512, 16x32) ----------
    #pragma unroll
    for (int k = 0; k < 16; ++k) {
        short8 afrag[4];
        if (k < 8) {                                   // x-half: global (L2-hot)
            #pragma unroll
            for (int mf = 0; mf < 4; ++mf)
                afrag[mf] = *(const short8*)(aptr[mf] + k * 32);
        } else {                                       // nm-half: LDS
            #pragma unroll
            for (int mf = 0; mf < 4; ++mf)
                afrag[mf] = *(const short8*)&AcNm[mf * 16 + lo16][(k - 8) * 32 + quad * 8];
        }
        short8 bfrag[4];
        #pragma unroll
        for (int nf = 0; nf < 4; ++nf)
            bfrag[nf] = *(const short8*)(bbase + k * 8192 + nf * 512);
        #pragma unroll
        for (int mf = 0; mf < 4; ++mf)
            #pragma unroll
            for (int nf = 0; nf < 4; ++nf)
                acc[mf][nf] = __builtin_amdgcn_mfma_f32_16x16x32_bf16(afrag[mf], bfrag[nf], acc[mf][nf], 0, 0, 0);
    }

    // ---------- Epilogue: bias + LN + ReLU, fully fused ----------
    __syncthreads();                                   // all K-loop AcNm reads done
    float* srp  = scr;                                 // [64][4][2] partial sums
    float* srow = scr + 512;                           // [64][2] mean/rstd

    float biasc[4], gc[4], oc[4];
    #pragma unroll
    for (int nf = 0; nf < 4; ++nf) {
        int col = wv * 64 + nf * 16 + lo16;
        biasc[nf] = b2[col];
        gc[nf] = lnS[col];
        oc[nf] = lnO[col];
    }
    #pragma unroll
    for (int mf = 0; mf < 4; ++mf)
        #pragma unroll
        for (int nf = 0; nf < 4; ++nf) acc[mf][nf] += biasc[nf];

    #pragma unroll
    for (int mf = 0; mf < 4; ++mf) {
        float s1[4], s2[4];
        #pragma unroll
        for (int r = 0; r < 4; ++r) {
            float v0 = acc[mf][0][r], v1 = acc[mf][1][r], v2 = acc[mf][2][r], v3 = acc[mf][3][r];
            s1[r] = v0 + v1 + v2 + v3;
            s2[r] = v0 * v0 + v1 * v1 + v2 * v2 + v3 * v3;
        }
        #pragma unroll
        for (int d = 1; d < 16; d <<= 1) {
            #pragma unroll
            for (int r = 0; r < 4; ++r) {
                s1[r] += __shfl_xor(s1[r], d, 64);
                s2[r] += __shfl_xor(s2[r], d, 64);
            }
        }
        if (lo16 == 0) {
            int row = mf * 16 + quad * 4;
            #pragma unroll
            for (int r = 0; r < 4; ++r) {
                srp[(row + r) * 8 + wv * 2    ] = s1[r];
                srp[(row + r) * 8 + wv * 2 + 1] = s2[r];
            }
        }
    }
    __syncthreads();
    if (t < 64) {
        float S1 = 0.f, S2 = 0.f;
        #pragma unroll
        for (int w = 0; w < 4; ++w) { S1 += srp[t * 8 + w * 2]; S2 += srp[t * 8 + w * 2 + 1]; }
        float mean = S1 * (1.0f / 256.0f);
        float var  = S2 * (1.0f / 256.0f) - mean * mean;
        float rstd = rsqrtf(var + 1e-5f);
        srow[t * 2] = mean; srow[t * 2 + 1] = rstd;
    }
    __syncthreads();

    // Normalize into AcNm (flat [64][256] bf16, global layout) ...
    unsigned short* obuf = &AcNm[0][0];
    #pragma unroll
    for (int mf = 0; mf < 4; ++mf) {
        #pragma unroll
        for (int r = 0; r < 4; ++r) {
            int row = mf * 16 + quad * 4 + r;
            float mean = srow[row * 2], rstd = srow[row * 2 + 1];
            #pragma unroll
            for (int nf = 0; nf < 4; ++nf) {
                float v = (acc[mf][nf][r] - mean) * rstd * gc[nf] + oc[nf];
                v = fmaxf(v, 0.0f);
                obuf[row * 256 + wv * 64 + nf * 16 + lo16] = f2bf(v);
            }
        }
    }
    __syncthreads();

    // ... then store flat & coalesced: 16 B/lane (bf16) or 32 B/lane (f32).
    #pragma unroll
    for (int it = 0; it < 8; ++it) {
        const int e = it * 2048 + t * 8;               // tile element index (8 per lane, one row)
        const long rg = r0 + (e >> 8);
        if (rg < MREAL) {
            uint4 w = *(const uint4*)(obuf + e);
            if (OUTF32) {
                float* dp = (float*)dstv + r0 * 256 + e;
                float4 f0, f1;
                f0.x = bits2f(w.x << 16); f0.y = bits2f(w.x & 0xFFFF0000u);
                f0.z = bits2f(w.y << 16); f0.w = bits2f(w.y & 0xFFFF0000u);
                f1.x = bits2f(w.z << 16); f1.y = bits2f(w.z & 0xFFFF0000u);
                f1.z = bits2f(w.w << 16); f1.w = bits2f(w.w & 0xFFFF0000u);
                *(float4*)dp = f0;
                *(float4*)(dp + 4) = f1;
            } else {
                *(uint4*)((unsigned short*)dstv + r0 * 256 + e) = w;
            }
        }
    }
}

// ---------------------------------------------------------------------------
extern "C" void kernel_launch(void* const* d_in, const int* in_sizes, int n_in,
                              void* d_out, int out_size, void* d_ws, size_t ws_size,
                              hipStream_t stream) {
    const float* x0  = (const float*)d_in[0];  // 50000x256 f32
    const float* Ws  = (const float*)d_in[1];  // 3x256x256 f32
    const float* bs  = (const float*)d_in[2];  // 3x256 f32
    const float* Wn  = (const float*)d_in[3];  // 3x256x256 f32
    const float* bn  = (const float*)d_in[4];  // 3x256 f32
    const float* lnS = (const float*)d_in[5];  // 3x256 f32
    const float* lnO = (const float*)d_in[6];  // 3x256 f32
    const int* nbr   = (const int*)d_in[7];    // 50000x6 i32

    char* ws = (char*)d_ws;
    const size_t XBYTES = (size_t)MREAL * 256 * 2;               // 25,600,000 (bf16 state)
    unsigned short* xbf = (unsigned short*)ws;
    unsigned short* xA  = (unsigned short*)(ws + XBYTES);
    unsigned short* Bt  = (unsigned short*)(ws + 2 * XBYTES);    // 786,432 B
    float*          b2  = (float*)(ws + 2 * XBYTES + 786432);    // 3,072 B

    cvt_kernel <<<6250, 256, 0, stream>>>(x0, xbf);              // 6250*256*8 = 12.8M
    prep_kernel<<<1536, 256, 0, stream>>>(Ws, bs, Wn, bn, Bt, b2);
    step_kernel<false><<<NBLK, 256, 0, stream>>>(xbf, (void*)xA,  Bt,          b2,       lnS,       lnO,       nbr);
    step_kernel<false><<<NBLK, 256, 0, stream>>>(xA,  (void*)xbf, Bt + 131072, b2 + 256, lnS + 256, lnO + 256, nbr);
    step_kernel<true> <<<NBLK, 256, 0, stream>>>(xbf, d_out,      Bt + 262144, b2 + 512, lnS + 512, lnO + 512, nbr);
}

// Round 9
// 252.700 us; speedup vs baseline: 1.9500x; 1.2135x over previous
//
#include <hip/hip_runtime.h>
#include <stdint.h>

typedef uint32_t u32;
typedef __attribute__((ext_vector_type(8))) short short8;  // 8 bf16 (4 VGPRs) - MFMA A/B frag
typedef __attribute__((ext_vector_type(4))) float f32x4;   // MFMA C/D frag

#define MREAL 50000
#define NBLK  784        // 8 XCD stripes x 98 blocks x 64 rows = 50176 (>= 50000)

__device__ __forceinline__ float bits2f(u32 b) { float f; __builtin_memcpy(&f, &b, 4); return f; }
__device__ __forceinline__ float bf2f(unsigned short h) { return bits2f(((u32)h) << 16); }
__device__ __forceinline__ unsigned short f2bf(float f) {
    u32 u; __builtin_memcpy(&u, &f, 4);
    u32 r = u + 0x7FFFu + ((u >> 16) & 1u);   // RNE
    return (unsigned short)(r >> 16);
}
__device__ __forceinline__ void addbf8(uint4 v, float a[8]) {
    a[0] += bits2f(v.x << 16); a[1] += bits2f(v.x & 0xFFFF0000u);
    a[2] += bits2f(v.y << 16); a[3] += bits2f(v.y & 0xFFFF0000u);
    a[4] += bits2f(v.z << 16); a[5] += bits2f(v.z & 0xFFFF0000u);
    a[6] += bits2f(v.w << 16); a[7] += bits2f(v.w & 0xFFFF0000u);
}

// ---------------------------------------------------------------------------
// x0 (f32) -> bf16, 8 elements/thread.
// ---------------------------------------------------------------------------
__global__ void cvt_kernel(const float* __restrict__ in, unsigned short* __restrict__ out) {
    long i = ((long)blockIdx.x * 256 + threadIdx.x) * 8;
    float4 a = *(const float4*)(in + i);
    float4 b = *(const float4*)(in + i + 4);
    uint4 o;
    o.x = (u32)f2bf(a.x) | ((u32)f2bf(a.y) << 16);
    o.y = (u32)f2bf(a.z) | ((u32)f2bf(a.w) << 16);
    o.z = (u32)f2bf(b.x) | ((u32)f2bf(b.y) << 16);
    o.w = (u32)f2bf(b.z) | ((u32)f2bf(b.w) << 16);
    *(uint4*)(out + i) = o;
}

// ---------------------------------------------------------------------------
// Prep: Bt[step][kc][n][kkr] = bf16 of B^T chunk-packed, B = [Ws + I ; Wn]
// (512x256 per step, f32 inputs).  Also b2 = bs + bn (f32).
// ---------------------------------------------------------------------------
__global__ void prep_kernel(const float* __restrict__ Ws,
                            const float* __restrict__ bs,
                            const float* __restrict__ Wn,
                            const float* __restrict__ bn,
                            unsigned short* __restrict__ Bt,
                            float* __restrict__ b2) {
    int lin = blockIdx.x * 256 + threadIdx.x;      // 3*16*256*32 = 393216 total
    int kkr = lin & 31;
    int n   = (lin >> 5) & 255;
    int kc  = (lin >> 13) & 15;
    int s   = lin >> 17;
    int kk  = kc * 32 + kkr;
    float v;
    if (kk < 256) v = Ws[(s * 256 + kk) * 256 + n] + (kk == n ? 1.0f : 0.0f);
    else          v = Wn[(s * 256 + (kk - 256)) * 256 + n];
    Bt[lin] = f2bf(v);
    if (lin < 768) b2[lin] = bs[lin] + bn[lin];
}

// ---------------------------------------------------------------------------
// One fused step: y = [x | neigh_mean] @ [Ws+I ; Wn] + (bs+bn); LN; ReLU.
// BM=64 rows/block, 4 waves, each wave 64x64 (4x4 MFMA), barrier-free K-loop.
// Gather restructured for CONTIGUOUS loads — each half-wave (32 lanes x 16 B)
// covers one full 512 B neighbor row, so each gather load touches 8 cache
// lines instead of 64 (the round-7 vmem-pipe bottleneck). Neighbor indices
// pre-staged in LDS by wave 0 (int2, 8B-aligned).
// ---------------------------------------------------------------------------
template <bool OUTF32>
__global__ __launch_bounds__(256, 4) void step_kernel(
    const unsigned short* __restrict__ src,   // x (bf16, 50000x256)
    void* __restrict__ dstv,                  // bf16 or f32, 50000x256
    const unsigned short* __restrict__ Bt,    // this step's [16][256][32] bf16
    const float* __restrict__ b2,             // [256] combined bias (f32)
    const float* __restrict__ lnS,            // [256] ln_scale f32
    const float* __restrict__ lnO,            // [256] ln_offset f32
    const int* __restrict__ nbr)              // [50000][6]
{
    __shared__ unsigned short AcNm[64][264];  // nm tile; 528 B stride (odd x16) = bank-uniform
    __shared__ float scr[640];                // LN scratch: srp[512] + srow[128]
    __shared__ int ids[384];                  // 64 rows x 6 neighbor indices

    const int t    = threadIdx.x;
    const int wv   = t >> 6;
    const int lane = t & 63;
    const int lo16 = lane & 15;
    const int quad = lane >> 4;
    // XCD-stripe mapping: blocks b with b&7==x land on XCD x (round-robin);
    // XCD x owns the contiguous row stripe, so gather stays in its 4 MB L2.
    const long r0  = ((long)(blockIdx.x & 7) * 98 + (blockIdx.x >> 3)) * 64;

    // ---------- P-1: stage neighbor indices (wave 0; int2 = 8B-aligned) ----------
    if (t < 64) {
        long rc = r0 + t;
        if (rc > MREAL - 1) rc = MREAL - 1;
        const int* nb = nbr + rc * 6;
        int2 a = *(const int2*)nb;
        int2 b = *(const int2*)(nb + 2);
        int2 c = *(const int2*)(nb + 4);
        ids[t * 6 + 0] = a.x; ids[t * 6 + 1] = a.y;
        ids[t * 6 + 2] = b.x; ids[t * 6 + 3] = b.y;
        ids[t * 6 + 4] = c.x; ids[t * 6 + 5] = c.y;
    }
    __syncthreads();

    // ---------- P0: gather neighbor mean, CONTIGUOUS loads ----------
    // Half-wave per row: lane (t&31) covers col (t&31)*8 (16 B); t>>5 picks the
    // row within the group of 8. Each wave-load = 2 full rows = 8 cache lines.
    {
        const int colq = (t & 31) * 8;
        const int rsub = t >> 5;               // 0..7
        const float inv6 = 1.0f / 6.0f;
        #pragma unroll
        for (int it = 0; it < 8; ++it) {
            const int row = it * 8 + rsub;
            const int* idr = ids + row * 6;
            uint4 v0 = *(const uint4*)(src + (long)idr[0] * 256 + colq);
            uint4 v1 = *(const uint4*)(src + (long)idr[1] * 256 + colq);
            uint4 v2 = *(const uint4*)(src + (long)idr[2] * 256 + colq);
            uint4 v3 = *(const uint4*)(src + (long)idr[3] * 256 + colq);
            uint4 v4 = *(const uint4*)(src + (long)idr[4] * 256 + colq);
            uint4 v5 = *(const uint4*)(src + (long)idr[5] * 256 + colq);
            float a[8] = {0, 0, 0, 0, 0, 0, 0, 0};
            addbf8(v0, a); addbf8(v1, a); addbf8(v2, a);
            addbf8(v3, a); addbf8(v4, a); addbf8(v5, a);
            uint4 o;
            o.x = (u32)f2bf(a[0] * inv6) | ((u32)f2bf(a[1] * inv6) << 16);
            o.y = (u32)f2bf(a[2] * inv6) | ((u32)f2bf(a[3] * inv6) << 16);
            o.z = (u32)f2bf(a[4] * inv6) | ((u32)f2bf(a[5] * inv6) << 16);
            o.w = (u32)f2bf(a[6] * inv6) | ((u32)f2bf(a[7] * inv6) << 16);
            *(uint4*)&AcNm[row][colq] = o;
        }
    }

    // A-row global pointers (clamped for the tail block)
    const unsigned short* aptr[4];
    #pragma unroll
    for (int mf = 0; mf < 4; ++mf) {
        long r = r0 + mf * 16 + lo16;
        if (r >= MREAL) r = MREAL - 1;
        aptr[mf] = src + r * 256 + quad * 8;
    }
    // Per-lane B base: n = wv*64 + nf*16 + lo16; element addr = n*32 + quad*8.
    const unsigned short* bbase = Bt + ((long)(wv * 64 + lo16) * 32 + quad * 8);

    const f32x4 zero4 = {0.f, 0.f, 0.f, 0.f};
    f32x4 acc[4][4];
    #pragma unroll
    for (int mf = 0; mf < 4; ++mf)
        #pragma unroll
        for (int nf = 0; nf < 4; ++nf) acc[mf][nf] = zero4;

    __syncthreads();                                   // AcNm ready

    // ---------- K-loop: barrier-free, fully unrolled (K = 512, 16x32) ----------
    #pragma unroll
    for (int k = 0; k < 16; ++k) {
        short8 afrag[4];
        if (k < 8) {                                   // x-half: global (L2-hot)
            #pragma unroll
            for (int mf = 0; mf < 4; ++mf)
                afrag[mf] = *(const short8*)(aptr[mf] + k * 32);
        } else {                                       // nm-half: LDS
            #pragma unroll
            for (int mf = 0; mf < 4; ++mf)
                afrag[mf] = *(const short8*)&AcNm[mf * 16 + lo16][(k - 8) * 32 + quad * 8];
        }
        short8 bfrag[4];
        #pragma unroll
        for (int nf = 0; nf < 4; ++nf)
            bfrag[nf] = *(const short8*)(bbase + k * 8192 + nf * 512);
        #pragma unroll
        for (int mf = 0; mf < 4; ++mf)
            #pragma unroll
            for (int nf = 0; nf < 4; ++nf)
                acc[mf][nf] = __builtin_amdgcn_mfma_f32_16x16x32_bf16(afrag[mf], bfrag[nf], acc[mf][nf], 0, 0, 0);
    }

    // ---------- Epilogue: bias + LN + ReLU, fully fused ----------
    __syncthreads();                                   // all K-loop AcNm reads done
    float* srp  = scr;                                 // [64][4][2] partial sums
    float* srow = scr + 512;                           // [64][2] mean/rstd

    float biasc[4], gc[4], oc[4];
    #pragma unroll
    for (int nf = 0; nf < 4; ++nf) {
        int col = wv * 64 + nf * 16 + lo16;
        biasc[nf] = b2[col];
        gc[nf] = lnS[col];
        oc[nf] = lnO[col];
    }
    #pragma unroll
    for (int mf = 0; mf < 4; ++mf)
        #pragma unroll
        for (int nf = 0; nf < 4; ++nf) acc[mf][nf] += biasc[nf];

    #pragma unroll
    for (int mf = 0; mf < 4; ++mf) {
        float s1[4], s2[4];
        #pragma unroll
        for (int r = 0; r < 4; ++r) {
            float v0 = acc[mf][0][r], v1 = acc[mf][1][r], v2 = acc[mf][2][r], v3 = acc[mf][3][r];
            s1[r] = v0 + v1 + v2 + v3;
            s2[r] = v0 * v0 + v1 * v1 + v2 * v2 + v3 * v3;
        }
        #pragma unroll
        for (int d = 1; d < 16; d <<= 1) {
            #pragma unroll
            for (int r = 0; r < 4; ++r) {
                s1[r] += __shfl_xor(s1[r], d, 64);
                s2[r] += __shfl_xor(s2[r], d, 64);
            }
        }
        if (lo16 == 0) {
            int row = mf * 16 + quad * 4;
            #pragma unroll
            for (int r = 0; r < 4; ++r) {
                srp[(row + r) * 8 + wv * 2    ] = s1[r];
                srp[(row + r) * 8 + wv * 2 + 1] = s2[r];
            }
        }
    }
    __syncthreads();
    if (t < 64) {
        float S1 = 0.f, S2 = 0.f;
        #pragma unroll
        for (int w = 0; w < 4; ++w) { S1 += srp[t * 8 + w * 2]; S2 += srp[t * 8 + w * 2 + 1]; }
        float mean = S1 * (1.0f / 256.0f);
        float var  = S2 * (1.0f / 256.0f) - mean * mean;
        float rstd = rsqrtf(var + 1e-5f);
        srow[t * 2] = mean; srow[t * 2 + 1] = rstd;
    }
    __syncthreads();

    // Normalize into AcNm (flat [64][256] bf16, global layout) ...
    unsigned short* obuf = &AcNm[0][0];
    #pragma unroll
    for (int mf = 0; mf < 4; ++mf) {
        #pragma unroll
        for (int r = 0; r < 4; ++r) {
            int row = mf * 16 + quad * 4 + r;
            float mean = srow[row * 2], rstd = srow[row * 2 + 1];
            #pragma unroll
            for (int nf = 0; nf < 4; ++nf) {
                float v = (acc[mf][nf][r] - mean) * rstd * gc[nf] + oc[nf];
                v = fmaxf(v, 0.0f);
                obuf[row * 256 + wv * 64 + nf * 16 + lo16] = f2bf(v);
            }
        }
    }
    __syncthreads();

    // ... then store flat & coalesced: 16 B/lane (bf16) or 32 B/lane (f32).
    #pragma unroll
    for (int it = 0; it < 8; ++it) {
        const int e = it * 2048 + t * 8;               // tile element index (8 per lane, one row)
        const long rg = r0 + (e >> 8);
        if (rg < MREAL) {
            uint4 w = *(const uint4*)(obuf + e);
            if (OUTF32) {
                float* dp = (float*)dstv + r0 * 256 + e;
                float4 f0, f1;
                f0.x = bits2f(w.x << 16); f0.y = bits2f(w.x & 0xFFFF0000u);
                f0.z = bits2f(w.y << 16); f0.w = bits2f(w.y & 0xFFFF0000u);
                f1.x = bits2f(w.z << 16); f1.y = bits2f(w.z & 0xFFFF0000u);
                f1.z = bits2f(w.w << 16); f1.w = bits2f(w.w & 0xFFFF0000u);
                *(float4*)dp = f0;
                *(float4*)(dp + 4) = f1;
            } else {
                *(uint4*)((unsigned short*)dstv + r0 * 256 + e) = w;
            }
        }
    }
}

// ---------------------------------------------------------------------------
extern "C" void kernel_launch(void* const* d_in, const int* in_sizes, int n_in,
                              void* d_out, int out_size, void* d_ws, size_t ws_size,
                              hipStream_t stream) {
    const float* x0  = (const float*)d_in[0];  // 50000x256 f32
    const float* Ws  = (const float*)d_in[1];  // 3x256x256 f32
    const float* bs  = (const float*)d_in[2];  // 3x256 f32
    const float* Wn  = (const float*)d_in[3];  // 3x256x256 f32
    const float* bn  = (const float*)d_in[4];  // 3x256 f32
    const float* lnS = (const float*)d_in[5];  // 3x256 f32
    const float* lnO = (const float*)d_in[6];  // 3x256 f32
    const int* nbr   = (const int*)d_in[7];    // 50000x6 i32

    char* ws = (char*)d_ws;
    const size_t XBYTES = (size_t)MREAL * 256 * 2;               // 25,600,000 (bf16 state)
    unsigned short* xbf = (unsigned short*)ws;
    unsigned short* xA  = (unsigned short*)(ws + XBYTES);
    unsigned short* Bt  = (unsigned short*)(ws + 2 * XBYTES);    // 786,432 B
    float*          b2  = (float*)(ws + 2 * XBYTES + 786432);    // 3,072 B

    cvt_kernel <<<6250, 256, 0, stream>>>(x0, xbf);              // 6250*256*8 = 12.8M
    prep_kernel<<<1536, 256, 0, stream>>>(Ws, bs, Wn, bn, Bt, b2);
    step_kernel<false><<<NBLK, 256, 0, stream>>>(xbf, (void*)xA,  Bt,          b2,       lnS,       lnO,       nbr);
    step_kernel<false><<<NBLK, 256, 0, stream>>>(xA,  (void*)xbf, Bt + 131072, b2 + 256, lnS + 256, lnO + 256, nbr);
    step_kernel<true> <<<NBLK, 256, 0, stream>>>(xbf, d_out,      Bt + 262144, b2 + 512, lnS + 512, lnO + 512, nbr);
}